// Round 3
// baseline (655.983 us; speedup 1.0000x reference)
//
#include <hip/hip_runtime.h>
#include <stdint.h>

typedef __attribute__((ext_vector_type(8))) short short8;
typedef __attribute__((ext_vector_type(4))) float floatx4;

#define Hh 384
#define Ww 384
#define Cc 11
#define Nn 32
#define PITCH 72  // elems; 144 B row stride keeps every 8-elem unit 16B-aligned

__device__ __forceinline__ unsigned short f2bf(float f) {
  union { float f; uint32_t u; } z; z.f = f;
  return (unsigned short)(z.u >> 16);
}
__device__ __forceinline__ float bf2f(unsigned short b) {
  union { uint32_t u; float f; } z; z.u = ((uint32_t)b) << 16;
  return z.f;
}

// lgkm-only barrier: LDS ordered, global prefetch loads stay in flight.
#define BAR() do {                                          \
    asm volatile("s_waitcnt lgkmcnt(0)" ::: "memory");      \
    __builtin_amdgcn_s_barrier();                           \
    asm volatile("" ::: "memory");                          \
  } while (0)

__global__ __launch_bounds__(512, 8)
void center_loss(const float* __restrict__ X, const float* __restrict__ Cen,
                 const int* __restrict__ Lab, float* __restrict__ Out) {
  // Single-buffered bf16 tiles, stored as swizzled 16B units:
  // unit u of row r lives at byte r*144 + (u ^ (r&7))*16  (bijective per row).
  __shared__ __align__(16) unsigned short Alds[64 * PITCH];  // A[i][k]  (x rows)
  __shared__ __align__(16) unsigned short Blds[64 * PITCH];  // Bt[j][k] (centers cols)
  __shared__ float red[8];

  // XCD swizzle: all 36 blocks of one n share an XCD.
  const int bx   = blockIdx.x;
  const int xcd  = bx & 7;
  const int slot = bx >> 3;
  const int grp  = slot / 36;
  const int t36  = slot - grp * 36;
  const int n    = xcd + (grp << 3);
  const int ib = t36 / 6;
  const int jb = t36 - ib * 6;
  const int i0 = ib << 6, j0 = jb << 6;

  const int t   = threadIdx.x;
  const int l   = t & 63;
  const int w   = t >> 6;          // 0..7
  const int wr  = (w >> 2) << 5;   // 0 / 32   (wave's output rows)
  const int wc  = (w & 3) << 4;    // 0/16/32/48 (wave's output cols)
  const int q4  = l >> 4;
  const int l16 = l & 15;
  const int e8  = l16 & 7;
  // A staging: thread t owns row ar, 8-col unit ac
  const int ar  = t >> 3;          // 0..63
  const int ac  = t & 7;
  const int aoff = ar * PITCH + ((ac ^ (ar & 7)) << 3);
  // B staging: thread t owns Bt row l, k-unit w
  const int boff = l * PITCH + ((w ^ (l & 7)) << 3);

  // Iteration-invariant fragment read offsets (elems)
  const int fa0[2] = { (wr +      l16) * PITCH + (((0 + q4) ^ e8) << 3),
                       (wr +      l16) * PITCH + (((4 + q4) ^ e8) << 3) };
  const int fa1[2] = { (wr + 16 + l16) * PITCH + (((0 + q4) ^ e8) << 3),
                       (wr + 16 + l16) * PITCH + (((4 + q4) ^ e8) << 3) };
  const int fb0[2] = { (wc +      l16) * PITCH + (((0 + q4) ^ e8) << 3),
                       (wc +      l16) * PITCH + (((4 + q4) ^ e8) << 3) };

  const size_t plane = (size_t)Hh * Ww;
  const float* xrow = X   + (size_t)n * Cc * plane + (size_t)(i0 + ar) * Ww + (ac << 3);
  const float* crow = Cen + (size_t)n * Cc * plane + (size_t)(w << 3) * Ww + j0 + l;

  float m[8], s[8];
#pragma unroll
  for (int i = 0; i < 8; ++i) { m[i] = -3.0e38f; s[i] = 0.0f; }
  floatx4 acc[2];
  acc[0] = (floatx4){0.f, 0.f, 0.f, 0.f};
  acc[1] = (floatx4){0.f, 0.f, 0.f, 0.f};

  // One-deep register prefetch: tile i+1 lives here during iteration i.
  float4 pa[2];
  float  pb[8];

#define LOADT(CC, KK) do {                                                     \
    const float* ap_ = xrow + (size_t)(CC) * plane + ((KK) << 6);              \
    pa[0] = *reinterpret_cast<const float4*>(ap_);                             \
    pa[1] = *reinterpret_cast<const float4*>(ap_ + 4);                         \
    const float* bp_ = crow + (size_t)(CC) * plane + (size_t)((KK) << 6) * Ww; \
    _Pragma("unroll")                                                          \
    for (int u_ = 0; u_ < 8; ++u_) pb[u_] = bp_[(size_t)u_ * Ww];              \
  } while (0)

#define STAGE() do {                                                           \
    short8 av_;                                                                \
    _Pragma("unroll")                                                          \
    for (int i_ = 0; i_ < 4; ++i_) {                                           \
      av_[i_]     = (short)f2bf(pa[0][i_]);                                    \
      av_[i_ + 4] = (short)f2bf(pa[1][i_]);                                    \
    }                                                                          \
    *reinterpret_cast<short8*>(&Alds[aoff]) = av_;                             \
    short8 bv_;                                                                \
    _Pragma("unroll")                                                          \
    for (int u_ = 0; u_ < 8; ++u_) bv_[u_] = (short)f2bf(pb[u_]);              \
    *reinterpret_cast<short8*>(&Blds[boff]) = bv_;                             \
  } while (0)

  // res = x^2 + c^2 - 2*mm carried as acc = mm - 0.5*(x^2 + c^2); res = -2*acc.
#define COMPUTE() do {                                                         \
    if (kbC == jb) { /* A tile cols are j0..j0+63: grab x[i][j]^2 */           \
      _Pragma("unroll") for (int fr_ = 0; fr_ < 2; ++fr_)                      \
      _Pragma("unroll") for (int r_ = 0; r_ < 4; ++r_) {                       \
        const int pr_ = wr + (fr_ << 4) + (q4 << 2) + r_;                      \
        const int pc_ = wc + l16;                                              \
        float xv_ = bf2f(Alds[pr_ * PITCH + (((pc_ >> 3) ^ (pr_ & 7)) << 3) + (pc_ & 7)]); \
        acc[fr_][r_] -= 0.5f * xv_ * xv_;                                      \
      }                                                                        \
    }                                                                          \
    if (kbC == ib) { /* Bt tile k-range is i0..i0+63: grab centers[i][j]^2 */  \
      _Pragma("unroll") for (int fr_ = 0; fr_ < 2; ++fr_)                      \
      _Pragma("unroll") for (int r_ = 0; r_ < 4; ++r_) {                       \
        const int pr_ = wr + (fr_ << 4) + (q4 << 2) + r_;                      \
        const int pc_ = wc + l16;                                              \
        float cv_ = bf2f(Blds[pc_ * PITCH + (((pr_ >> 3) ^ (pc_ & 7)) << 3) + (pr_ & 7)]); \
        acc[fr_][r_] -= 0.5f * cv_ * cv_;                                      \
      }                                                                        \
    }                                                                          \
    _Pragma("unroll") for (int ks_ = 0; ks_ < 2; ++ks_) {                      \
      short8 a0_ = *reinterpret_cast<const short8*>(&Alds[fa0[ks_]]);          \
      short8 a1_ = *reinterpret_cast<const short8*>(&Alds[fa1[ks_]]);          \
      short8 b0_ = *reinterpret_cast<const short8*>(&Blds[fb0[ks_]]);          \
      acc[0] = __builtin_amdgcn_mfma_f32_16x16x32_bf16(a0_, b0_, acc[0], 0, 0, 0); \
      acc[1] = __builtin_amdgcn_mfma_f32_16x16x32_bf16(a1_, b0_, acc[1], 0, 0, 0); \
    }                                                                          \
    if (kbC == 5) { /* channel boundary: online softmax update */              \
      _Pragma("unroll") for (int fr_ = 0; fr_ < 2; ++fr_)                      \
      _Pragma("unroll") for (int r_ = 0; r_ < 4; ++r_) {                       \
        const int idx_ = (fr_ << 2) + r_;                                      \
        float res_ = -2.0f * acc[fr_][r_];                                     \
        float mi_ = m[idx_];                                                   \
        if (res_ <= mi_) {                                                     \
          s[idx_] += __expf(res_ - mi_);                                       \
        } else {                                                               \
          s[idx_] = s[idx_] * __expf(mi_ - res_) + 1.0f;                       \
          m[idx_] = res_;                                                      \
        }                                                                      \
        acc[fr_][r_] = 0.0f;                                                   \
      }                                                                        \
    }                                                                          \
  } while (0)

  // prologue: tile 0 into regs
  LOADT(0, 0);

  int kbC = 0;            // k-block of tile being computed
  int kbL = 1, cL = 0;    // next tile to load

  for (int it = 0; it < 66; ++it) {
    BAR();                 // previous iteration's LDS reads complete
    STAGE();               // regs (tile it) -> LDS
    if (it < 65) {         // issue tile it+1 loads; in flight across compute
      LOADT(cL, kbL);
      ++kbL; if (kbL == 6) { kbL = 0; ++cL; }
    }
    BAR();                 // LDS writes visible
    COMPUTE();
    ++kbC; if (kbC == 6) kbC = 0;
  }

  // ---- max(softmax) = 1/s ; weight by label; clip; reduce ----
  float local = 0.0f;
  const int* lb = Lab + (size_t)n * plane;
#pragma unroll
  for (int fr = 0; fr < 2; ++fr)
#pragma unroll
    for (int r = 0; r < 4; ++r) {
      const int idx = (fr << 2) + r;
      const int pr = i0 + wr + (fr << 4) + (q4 << 2) + r;
      const int pc = j0 + wc + l16;
      float val = 1.0f / s[idx];
      float d = val * (float)lb[pr * Ww + pc];
      d = fminf(fmaxf(d, 1e-12f), 1e12f);
      local += d;
    }
#pragma unroll
  for (int off = 32; off > 0; off >>= 1) local += __shfl_down(local, off, 64);
  if (l == 0) red[w] = local;
  __syncthreads();
  if (t == 0) {
    float bs = (red[0] + red[1] + red[2] + red[3] +
                red[4] + red[5] + red[6] + red[7]) * (1.0f / 4718592.0f);
    atomicAdd(Out, bs);
  }
}

extern "C" void kernel_launch(void* const* d_in, const int* in_sizes, int n_in,
                              void* d_out, int out_size, void* d_ws, size_t ws_size,
                              hipStream_t stream) {
  const float* X   = (const float*)d_in[0];
  const float* Cen = (const float*)d_in[1];
  const int*   Lab = (const int*)d_in[2];
  float* Out = (float*)d_out;
  hipMemsetAsync(Out, 0, (size_t)out_size * sizeof(float), stream);
  hipLaunchKernelGGL(center_loss, dim3(Nn * 36), dim3(512), 0, stream,
                     X, Cen, Lab, Out);
}

// Round 4
// 544.971 us; speedup vs baseline: 1.2037x; 1.2037x over previous
//
#include <hip/hip_runtime.h>
#include <stdint.h>

typedef __attribute__((ext_vector_type(8))) short short8;
typedef __attribute__((ext_vector_type(4))) float floatx4;
typedef __attribute__((ext_vector_type(4))) unsigned short u16x4;

#define Hh 384
#define Ww 384
#define Cc 11
#define Nn 32
#define PITCH 72  // 64 + 8 pad bf16 elems; 144 B rows: 16B-aligned

__device__ __forceinline__ unsigned short f2bf(float f) {
  union { float f; uint32_t u; } z; z.f = f;
  return (unsigned short)(z.u >> 16);
}
__device__ __forceinline__ float bf2f(unsigned short b) {
  union { uint32_t u; float f; } z; z.u = ((uint32_t)b) << 16;
  return z.f;
}

// ---------------------------------------------------------------------------
// Kernel 1: per-channel-chunk partial online softmax. Round-0 inner loop
// verbatim (best measured: 218 us steady); only the channel range and the
// (m,s) workspace write differ. Grid 2304 = 2 chunks x 1152 -> 9 blocks/CU,
// 8 resident (LDS 18.9KB, VGPR 64) vs round-0's grid-limited 4.5.
// ---------------------------------------------------------------------------
__global__ __launch_bounds__(256, 4)
void center_partial(const float* __restrict__ X, const float* __restrict__ Cen,
                    float2* __restrict__ Ws) {
  __shared__ __align__(16) unsigned short Alds[64 * PITCH];  // A[i][k]  (x rows)
  __shared__ __align__(16) unsigned short Blds[64 * PITCH];  // Bt[j][k] (centers cols)

  const int bx    = blockIdx.x;
  const int chunk = (bx >= 1152) ? 1 : 0;       // 1152 % 8 == 0: keeps XCD map
  const int bxl   = bx - chunk * 1152;
  const int c0    = chunk * 6;
  const int NT    = chunk ? 30 : 36;            // (5 or 6 channels) * 6 k-tiles

  const int xcd  = bxl & 7;
  const int slot = bxl >> 3;
  const int grp  = slot / 36;
  const int t36  = slot - grp * 36;
  const int n    = xcd + (grp << 3);
  const int ib = t36 / 6;
  const int jb = t36 - ib * 6;
  const int i0 = ib << 6, j0 = jb << 6;

  const int t   = threadIdx.x;
  const int l   = t & 63;
  const int w   = t >> 6;
  const int wr  = (w >> 1) << 5;
  const int wc  = (w & 1) << 5;
  const int q4  = l >> 4;
  const int l16 = l & 15;
  const int sa  = t & 15;            // A staging: col segment
  const int sr  = t >> 4;            // A staging: row base

  const size_t plane = (size_t)Hh * Ww;
  const float* xbase = X   + ((size_t)n * Cc + c0) * plane;
  const float* cbase = Cen + ((size_t)n * Cc + c0) * plane;

  float m[16], s[16];
#pragma unroll
  for (int i = 0; i < 16; ++i) { m[i] = -3.0e38f; s[i] = 0.0f; }

  floatx4 acc[2][2];
  float ev[16];
#pragma unroll
  for (int a = 0; a < 2; ++a)
#pragma unroll
    for (int b = 0; b < 2; ++b) acc[a][b] = (floatx4){0.f, 0.f, 0.f, 0.f};
#pragma unroll
  for (int i = 0; i < 16; ++i) ev[i] = 0.0f;

  float4 pa[4];
  float  pb[16];

  {  // initial load: (c=c0, kb=0)
    const float* ap = xbase + (size_t)(i0 + sr) * Ww + (sa << 2);
#pragma unroll
    for (int p = 0; p < 4; ++p)
      pa[p] = *reinterpret_cast<const float4*>(ap + (size_t)(p * 16) * Ww);
#pragma unroll
    for (int p = 0; p < 2; ++p) {
      const int kbase = (w << 3) + (p << 5);
      const float* bp = cbase + (size_t)kbase * Ww + j0 + l;
#pragma unroll
      for (int u = 0; u < 8; ++u) pb[p * 8 + u] = bp[(size_t)u * Ww];
    }
  }

  int c = 0, kb = 0;
  for (int it = 0; it < NT; ++it) {
    __syncthreads();

#pragma unroll
    for (int p = 0; p < 4; ++p) {
      u16x4 pk;
      pk.x = f2bf(pa[p].x); pk.y = f2bf(pa[p].y);
      pk.z = f2bf(pa[p].z); pk.w = f2bf(pa[p].w);
      *reinterpret_cast<u16x4*>(&Alds[(sr + 16 * p) * PITCH + (sa << 2)]) = pk;
    }
#pragma unroll
    for (int p = 0; p < 2; ++p) {
      const int kbase = (w << 3) + (p << 5);
      short8 pk;
#pragma unroll
      for (int u = 0; u < 8; ++u) pk[u] = (short)f2bf(pb[p * 8 + u]);
      *reinterpret_cast<short8*>(&Blds[l * PITCH + kbase]) = pk;
    }

    int kn = kb + 1, cn = c;
    if (kn == 6) { kn = 0; cn = c + 1; }
    float4 na[4];
    float  nb[16];
    if (it < NT - 1) {
      const float* xb = xbase + (size_t)cn * plane;
      const float* cb = cbase + (size_t)cn * plane;
      const float* ap = xb + (size_t)(i0 + sr) * Ww + (kn << 6) + (sa << 2);
#pragma unroll
      for (int p = 0; p < 4; ++p)
        na[p] = *reinterpret_cast<const float4*>(ap + (size_t)(p * 16) * Ww);
#pragma unroll
      for (int p = 0; p < 2; ++p) {
        const int kbase = (w << 3) + (p << 5);
        const float* bp = cb + (size_t)((kn << 6) + kbase) * Ww + j0 + l;
#pragma unroll
        for (int u = 0; u < 8; ++u) nb[p * 8 + u] = bp[(size_t)u * Ww];
      }
    }

    __syncthreads();

    if (kb == jb) {
#pragma unroll
      for (int fr = 0; fr < 2; ++fr)
#pragma unroll
        for (int fc = 0; fc < 2; ++fc)
#pragma unroll
          for (int r = 0; r < 4; ++r) {
            const int idx = ((fr << 1) + fc) * 4 + r;
            const int pr = wr + (fr << 4) + (q4 << 2) + r;
            const int pc = wc + (fc << 4) + l16;
            float xv = bf2f(Alds[pr * PITCH + pc]);
            ev[idx] += xv * xv;
          }
    }
    if (kb == ib) {
#pragma unroll
      for (int fr = 0; fr < 2; ++fr)
#pragma unroll
        for (int fc = 0; fc < 2; ++fc)
#pragma unroll
          for (int r = 0; r < 4; ++r) {
            const int idx = ((fr << 1) + fc) * 4 + r;
            const int pr = wr + (fr << 4) + (q4 << 2) + r;
            const int pc = wc + (fc << 4) + l16;
            float cv = bf2f(Blds[pc * PITCH + pr]);
            ev[idx] += cv * cv;
          }
    }

#pragma unroll
    for (int ks = 0; ks < 2; ++ks) {
      const int ko = (ks << 5) + (q4 << 3);
      short8 a0 = *reinterpret_cast<const short8*>(&Alds[(wr +      l16) * PITCH + ko]);
      short8 a1 = *reinterpret_cast<const short8*>(&Alds[(wr + 16 + l16) * PITCH + ko]);
      short8 b0 = *reinterpret_cast<const short8*>(&Blds[(wc +      l16) * PITCH + ko]);
      short8 b1 = *reinterpret_cast<const short8*>(&Blds[(wc + 16 + l16) * PITCH + ko]);
      acc[0][0] = __builtin_amdgcn_mfma_f32_16x16x32_bf16(a0, b0, acc[0][0], 0, 0, 0);
      acc[0][1] = __builtin_amdgcn_mfma_f32_16x16x32_bf16(a0, b1, acc[0][1], 0, 0, 0);
      acc[1][0] = __builtin_amdgcn_mfma_f32_16x16x32_bf16(a1, b0, acc[1][0], 0, 0, 0);
      acc[1][1] = __builtin_amdgcn_mfma_f32_16x16x32_bf16(a1, b1, acc[1][1], 0, 0, 0);
    }

    if (kb == 5) {
#pragma unroll
      for (int fr = 0; fr < 2; ++fr)
#pragma unroll
        for (int fc = 0; fc < 2; ++fc)
#pragma unroll
          for (int r = 0; r < 4; ++r) {
            const int idx = ((fr << 1) + fc) * 4 + r;
            float res = ev[idx] - 2.0f * acc[fr][fc][r];
            float mi = m[idx];
            if (res <= mi) {
              s[idx] += __expf(res - mi);
            } else {
              s[idx] = s[idx] * __expf(mi - res) + 1.0f;
              m[idx] = res;
            }
            acc[fr][fc][r] = 0.0f;
            ev[idx] = 0.0f;
          }
    }

    kb = kn; c = cn;
#pragma unroll
    for (int p = 0; p < 4; ++p) pa[p] = na[p];
#pragma unroll
    for (int p = 0; p < 16; ++p) pb[p] = nb[p];
  }

  // ---- write partial (m, s) per output element ----
  float2* wsk = Ws + ((size_t)chunk * Nn + n) * plane;
#pragma unroll
  for (int fr = 0; fr < 2; ++fr)
#pragma unroll
    for (int fc = 0; fc < 2; ++fc)
#pragma unroll
      for (int r = 0; r < 4; ++r) {
        const int idx = ((fr << 1) + fc) * 4 + r;
        const int pr = i0 + wr + (fr << 4) + (q4 << 2) + r;
        const int pc = j0 + wc + (fc << 4) + l16;
        float2 v; v.x = m[idx]; v.y = s[idx];
        wsk[(size_t)pr * Ww + pc] = v;
      }
}

// ---------------------------------------------------------------------------
// Kernel 2: merge the two (m,s) partials, apply label/clip, reduce.
// 4718592 elements = 4608 blocks x 256 threads x 4 grid-stride passes exactly.
// ---------------------------------------------------------------------------
__global__ __launch_bounds__(256)
void center_merge(const float2* __restrict__ Ws, const int* __restrict__ Lab,
                  float* __restrict__ Out) {
  __shared__ float red[4];
  const size_t NP = (size_t)Nn * Hh * Ww;          // 4718592
  const size_t stride = 4608ull * 256;
  size_t e = (size_t)blockIdx.x * 256 + threadIdx.x;
  float local = 0.0f;
#pragma unroll
  for (int u = 0; u < 4; ++u, e += stride) {
    float2 a = Ws[e];
    float2 b = Ws[NP + e];
    float M = fmaxf(a.x, b.x);
    float S = a.y * __expf(a.x - M) + b.y * __expf(b.x - M);
    float d = (1.0f / S) * (float)Lab[e];
    d = fminf(fmaxf(d, 1e-12f), 1e12f);
    local += d;
  }
  const int l = threadIdx.x & 63, w = threadIdx.x >> 6;
#pragma unroll
  for (int off = 32; off > 0; off >>= 1) local += __shfl_down(local, off, 64);
  if (l == 0) red[w] = local;
  __syncthreads();
  if (threadIdx.x == 0)
    atomicAdd(Out, (red[0] + red[1] + red[2] + red[3]) * (1.0f / 4718592.0f));
}

// ---------------------------------------------------------------------------
// Fallback: round-0 monolithic kernel (218 us steady), used if ws too small.
// ---------------------------------------------------------------------------
__global__ __launch_bounds__(256, 4)
void center_loss_mono(const float* __restrict__ X, const float* __restrict__ Cen,
                      const int* __restrict__ Lab, float* __restrict__ Out) {
  __shared__ __align__(16) unsigned short Alds[64 * PITCH];
  __shared__ __align__(16) unsigned short Blds[64 * PITCH];
  __shared__ float red[4];

  const int bx   = blockIdx.x;
  const int xcd  = bx & 7;
  const int slot = bx >> 3;
  const int grp  = slot / 36;
  const int t36  = slot - grp * 36;
  const int n    = xcd + (grp << 3);
  const int ib = t36 / 6;
  const int jb = t36 - ib * 6;
  const int i0 = ib << 6, j0 = jb << 6;

  const int t   = threadIdx.x;
  const int l   = t & 63;
  const int w   = t >> 6;
  const int wr  = (w >> 1) << 5;
  const int wc  = (w & 1) << 5;
  const int q4  = l >> 4;
  const int l16 = l & 15;
  const int sa  = t & 15;
  const int sr  = t >> 4;

  const size_t plane = (size_t)Hh * Ww;
  const float* xbase = X   + (size_t)n * Cc * plane;
  const float* cbase = Cen + (size_t)n * Cc * plane;

  float m[16], s[16];
#pragma unroll
  for (int i = 0; i < 16; ++i) { m[i] = -3.0e38f; s[i] = 0.0f; }
  floatx4 acc[2][2];
  float ev[16];
#pragma unroll
  for (int a = 0; a < 2; ++a)
#pragma unroll
    for (int b = 0; b < 2; ++b) acc[a][b] = (floatx4){0.f, 0.f, 0.f, 0.f};
#pragma unroll
  for (int i = 0; i < 16; ++i) ev[i] = 0.0f;

  float4 pa[4];
  float  pb[16];
  {
    const float* ap = xbase + (size_t)(i0 + sr) * Ww + (sa << 2);
#pragma unroll
    for (int p = 0; p < 4; ++p)
      pa[p] = *reinterpret_cast<const float4*>(ap + (size_t)(p * 16) * Ww);
#pragma unroll
    for (int p = 0; p < 2; ++p) {
      const int kbase = (w << 3) + (p << 5);
      const float* bp = cbase + (size_t)kbase * Ww + j0 + l;
#pragma unroll
      for (int u = 0; u < 8; ++u) pb[p * 8 + u] = bp[(size_t)u * Ww];
    }
  }

  int c = 0, kb = 0;
  for (int it = 0; it < 66; ++it) {
    __syncthreads();
#pragma unroll
    for (int p = 0; p < 4; ++p) {
      u16x4 pk;
      pk.x = f2bf(pa[p].x); pk.y = f2bf(pa[p].y);
      pk.z = f2bf(pa[p].z); pk.w = f2bf(pa[p].w);
      *reinterpret_cast<u16x4*>(&Alds[(sr + 16 * p) * PITCH + (sa << 2)]) = pk;
    }
#pragma unroll
    for (int p = 0; p < 2; ++p) {
      const int kbase = (w << 3) + (p << 5);
      short8 pk;
#pragma unroll
      for (int u = 0; u < 8; ++u) pk[u] = (short)f2bf(pb[p * 8 + u]);
      *reinterpret_cast<short8*>(&Blds[l * PITCH + kbase]) = pk;
    }
    int kn = kb + 1, cn = c;
    if (kn == 6) { kn = 0; cn = c + 1; }
    float4 na[4];
    float  nb[16];
    if (it < 65) {
      const float* xb = xbase + (size_t)cn * plane;
      const float* cb = cbase + (size_t)cn * plane;
      const float* ap = xb + (size_t)(i0 + sr) * Ww + (kn << 6) + (sa << 2);
#pragma unroll
      for (int p = 0; p < 4; ++p)
        na[p] = *reinterpret_cast<const float4*>(ap + (size_t)(p * 16) * Ww);
#pragma unroll
      for (int p = 0; p < 2; ++p) {
        const int kbase = (w << 3) + (p << 5);
        const float* bp = cb + (size_t)((kn << 6) + kbase) * Ww + j0 + l;
#pragma unroll
        for (int u = 0; u < 8; ++u) nb[p * 8 + u] = bp[(size_t)u * Ww];
      }
    }
    __syncthreads();
    if (kb == jb) {
#pragma unroll
      for (int fr = 0; fr < 2; ++fr)
#pragma unroll
        for (int fc = 0; fc < 2; ++fc)
#pragma unroll
          for (int r = 0; r < 4; ++r) {
            const int idx = ((fr << 1) + fc) * 4 + r;
            const int pr = wr + (fr << 4) + (q4 << 2) + r;
            const int pc = wc + (fc << 4) + l16;
            float xv = bf2f(Alds[pr * PITCH + pc]);
            ev[idx] += xv * xv;
          }
    }
    if (kb == ib) {
#pragma unroll
      for (int fr = 0; fr < 2; ++fr)
#pragma unroll
        for (int fc = 0; fc < 2; ++fc)
#pragma unroll
          for (int r = 0; r < 4; ++r) {
            const int idx = ((fr << 1) + fc) * 4 + r;
            const int pr = wr + (fr << 4) + (q4 << 2) + r;
            const int pc = wc + (fc << 4) + l16;
            float cv = bf2f(Blds[pc * PITCH + pr]);
            ev[idx] += cv * cv;
          }
    }
#pragma unroll
    for (int ks = 0; ks < 2; ++ks) {
      const int ko = (ks << 5) + (q4 << 3);
      short8 a0 = *reinterpret_cast<const short8*>(&Alds[(wr +      l16) * PITCH + ko]);
      short8 a1 = *reinterpret_cast<const short8*>(&Alds[(wr + 16 + l16) * PITCH + ko]);
      short8 b0 = *reinterpret_cast<const short8*>(&Blds[(wc +      l16) * PITCH + ko]);
      short8 b1 = *reinterpret_cast<const short8*>(&Blds[(wc + 16 + l16) * PITCH + ko]);
      acc[0][0] = __builtin_amdgcn_mfma_f32_16x16x32_bf16(a0, b0, acc[0][0], 0, 0, 0);
      acc[0][1] = __builtin_amdgcn_mfma_f32_16x16x32_bf16(a0, b1, acc[0][1], 0, 0, 0);
      acc[1][0] = __builtin_amdgcn_mfma_f32_16x16x32_bf16(a1, b0, acc[1][0], 0, 0, 0);
      acc[1][1] = __builtin_amdgcn_mfma_f32_16x16x32_bf16(a1, b1, acc[1][1], 0, 0, 0);
    }
    if (kb == 5) {
#pragma unroll
      for (int fr = 0; fr < 2; ++fr)
#pragma unroll
        for (int fc = 0; fc < 2; ++fc)
#pragma unroll
          for (int r = 0; r < 4; ++r) {
            const int idx = ((fr << 1) + fc) * 4 + r;
            float res = ev[idx] - 2.0f * acc[fr][fc][r];
            float mi = m[idx];
            if (res <= mi) {
              s[idx] += __expf(res - mi);
            } else {
              s[idx] = s[idx] * __expf(mi - res) + 1.0f;
              m[idx] = res;
            }
            acc[fr][fc][r] = 0.0f;
            ev[idx] = 0.0f;
          }
    }
    kb = kn; c = cn;
#pragma unroll
    for (int p = 0; p < 4; ++p) pa[p] = na[p];
#pragma unroll
    for (int p = 0; p < 16; ++p) pb[p] = nb[p];
  }

  float local = 0.0f;
  const int* lb = Lab + (size_t)n * plane;
#pragma unroll
  for (int fr = 0; fr < 2; ++fr)
#pragma unroll
    for (int fc = 0; fc < 2; ++fc)
#pragma unroll
      for (int r = 0; r < 4; ++r) {
        const int idx = ((fr << 1) + fc) * 4 + r;
        const int pr = i0 + wr + (fr << 4) + (q4 << 2) + r;
        const int pc = j0 + wc + (fc << 4) + l16;
        float val = 1.0f / s[idx];
        float d = val * (float)lb[pr * Ww + pc];
        d = fminf(fmaxf(d, 1e-12f), 1e12f);
        local += d;
      }
#pragma unroll
  for (int off = 32; off > 0; off >>= 1) local += __shfl_down(local, off, 64);
  if (l == 0) red[w] = local;
  __syncthreads();
  if (t == 0) {
    float bs = (red[0] + red[1] + red[2] + red[3]) * (1.0f / 4718592.0f);
    atomicAdd(Out, bs);
  }
}

extern "C" void kernel_launch(void* const* d_in, const int* in_sizes, int n_in,
                              void* d_out, int out_size, void* d_ws, size_t ws_size,
                              hipStream_t stream) {
  const float* X   = (const float*)d_in[0];
  const float* Cen = (const float*)d_in[1];
  const int*   Lab = (const int*)d_in[2];
  float* Out = (float*)d_out;
  hipMemsetAsync(Out, 0, (size_t)out_size * sizeof(float), stream);

  const size_t need = 2ull * Nn * Hh * Ww * sizeof(float2);  // 75.5 MB
  if (ws_size >= need && d_ws != nullptr) {
    float2* Ws = (float2*)d_ws;
    hipLaunchKernelGGL(center_partial, dim3(2 * Nn * 36), dim3(256), 0, stream,
                       X, Cen, Ws);
    hipLaunchKernelGGL(center_merge, dim3(4608), dim3(256), 0, stream,
                       Ws, Lab, Out);
  } else {
    hipLaunchKernelGGL(center_loss_mono, dim3(Nn * 36), dim3(256), 0, stream,
                       X, Cen, Lab, Out);
  }
}

// Round 5
// 492.047 us; speedup vs baseline: 1.3332x; 1.1076x over previous
//
#include <hip/hip_runtime.h>
#include <stdint.h>

typedef __attribute__((ext_vector_type(8))) short short8;
typedef __attribute__((ext_vector_type(4))) float floatx4;
typedef __attribute__((ext_vector_type(4))) unsigned short u16x4;

#define Hh 384
#define Ww 384
#define Cc 11
#define Nn 32
#define PITCH 72  // 64 + 8 pad bf16 elems; 144 B rows: 16B-aligned, conflict-free b128

__device__ __forceinline__ unsigned short f2bf(float f) {
  union { float f; uint32_t u; } z; z.f = f;
  return (unsigned short)(z.u >> 16);
}
__device__ __forceinline__ float bf2f(unsigned short b) {
  union { uint32_t u; float f; } z; z.u = ((uint32_t)b) << 16;
  return z.f;
}

// Raw barrier draining ONLY lgkmcnt (LDS ordering), not vmcnt: the global
// prefetch loads issued mid-iteration stay in flight across both barriers and
// are waited (by the compiler's own counted vmcnt) only at their register use
// in the NEXT iteration's staging — ~3-4K cycles of latency cover instead of
// the ~100 cycles __syncthreads' vmcnt(0) drain allowed.
#define BAR() do {                                          \
    asm volatile("s_waitcnt lgkmcnt(0)" ::: "memory");      \
    __builtin_amdgcn_s_barrier();                           \
    asm volatile("" ::: "memory");                          \
  } while (0)

__global__ __launch_bounds__(256, 4)
void center_loss(const float* __restrict__ X, const float* __restrict__ Cen,
                 const int* __restrict__ Lab, float* __restrict__ Out) {
  __shared__ __align__(16) unsigned short Alds[64 * PITCH];  // A[i][k]  (x rows)
  __shared__ __align__(16) unsigned short Blds[64 * PITCH];  // Bt[j][k] (centers cols)
  __shared__ float red[4];

  // XCD swizzle: dispatcher round-robins block i -> XCD i%8. Map so all 36
  // blocks of one n share an XCD: per-channel working set (1.18 MB) fits 4MB L2.
  const int bx   = blockIdx.x;
  const int xcd  = bx & 7;
  const int slot = bx >> 3;          // 0..143
  const int grp  = slot / 36;        // 0..3
  const int t36  = slot - grp * 36;
  const int n    = xcd + (grp << 3); // 0..31
  const int ib = t36 / 6;
  const int jb = t36 - ib * 6;
  const int i0 = ib << 6, j0 = jb << 6;

  const int t   = threadIdx.x;
  const int l   = t & 63;
  const int w   = t >> 6;
  const int wr  = (w >> 1) << 5;
  const int wc  = (w & 1) << 5;
  const int q4  = l >> 4;
  const int l16 = l & 15;
  const int sa  = t & 15;            // A staging: col segment
  const int sr  = t >> 4;            // A staging: row base

  const size_t plane = (size_t)Hh * Ww;
  const float* xbase = X   + (size_t)n * Cc * plane;
  const float* cbase = Cen + (size_t)n * Cc * plane;

  float m[16], s[16];
#pragma unroll
  for (int i = 0; i < 16; ++i) { m[i] = -3.0e38f; s[i] = 0.0f; }

  floatx4 acc[2][2];
  float ev[16];
#pragma unroll
  for (int a = 0; a < 2; ++a)
#pragma unroll
    for (int b = 0; b < 2; ++b) acc[a][b] = (floatx4){0.f, 0.f, 0.f, 0.f};
#pragma unroll
  for (int i = 0; i < 16; ++i) ev[i] = 0.0f;

  // ---- prefetch registers (tile for the CURRENT iteration) ----
  float4 pa[4];
  float  pb[16];

  // initial load: (c=0, kb=0)
  {
    const float* ap = xbase + (size_t)(i0 + sr) * Ww + (sa << 2);
#pragma unroll
    for (int p = 0; p < 4; ++p)
      pa[p] = *reinterpret_cast<const float4*>(ap + (size_t)(p * 16) * Ww);
#pragma unroll
    for (int p = 0; p < 2; ++p) {
      const int kbase = (w << 3) + (p << 5);
      const float* bp = cbase + (size_t)kbase * Ww + j0 + l;
#pragma unroll
      for (int u = 0; u < 8; ++u) pb[p * 8 + u] = bp[(size_t)u * Ww];
    }
  }

  int c = 0, kb = 0;
  for (int it = 0; it < 66; ++it) {
    BAR();             // previous iteration's LDS reads complete (lgkm only)

    // ---- stage current tile from regs into LDS ----
#pragma unroll
    for (int p = 0; p < 4; ++p) {
      u16x4 pk;
      pk.x = f2bf(pa[p].x); pk.y = f2bf(pa[p].y);
      pk.z = f2bf(pa[p].z); pk.w = f2bf(pa[p].w);
      *reinterpret_cast<u16x4*>(&Alds[(sr + 16 * p) * PITCH + (sa << 2)]) = pk;
    }
#pragma unroll
    for (int p = 0; p < 2; ++p) {
      const int kbase = (w << 3) + (p << 5);
      short8 pk;
#pragma unroll
      for (int u = 0; u < 8; ++u) pk[u] = (short)f2bf(pb[p * 8 + u]);
      *reinterpret_cast<short8*>(&Blds[l * PITCH + kbase]) = pk;
    }

    // ---- issue next tile's global loads (in flight across both barriers) ----
    int kn = kb + 1, cn = c;
    if (kn == 6) { kn = 0; cn = c + 1; }
    float4 na[4];
    float  nb[16];
    if (it < 65) {
      const float* xb = xbase + (size_t)cn * plane;
      const float* cb = cbase + (size_t)cn * plane;
      const float* ap = xb + (size_t)(i0 + sr) * Ww + (kn << 6) + (sa << 2);
#pragma unroll
      for (int p = 0; p < 4; ++p)
        na[p] = *reinterpret_cast<const float4*>(ap + (size_t)(p * 16) * Ww);
#pragma unroll
      for (int p = 0; p < 2; ++p) {
        const int kbase = (w << 3) + (p << 5);
        const float* bp = cb + (size_t)((kn << 6) + kbase) * Ww + j0 + l;
#pragma unroll
        for (int u = 0; u < 8; ++u) nb[p * 8 + u] = bp[(size_t)u * Ww];
      }
    }

    BAR();             // LDS writes visible (lgkm only; loads stay in flight)

    // ---- epilogue-term capture from LDS (free reuse of staged tiles) ----
    if (kb == jb) {    // A tile currently holds x[i0..][j0..j0+63]
#pragma unroll
      for (int fr = 0; fr < 2; ++fr)
#pragma unroll
        for (int fc = 0; fc < 2; ++fc)
#pragma unroll
          for (int r = 0; r < 4; ++r) {
            const int idx = ((fr << 1) + fc) * 4 + r;
            const int pr = wr + (fr << 4) + (q4 << 2) + r;
            const int pc = wc + (fc << 4) + l16;
            float xv = bf2f(Alds[pr * PITCH + pc]);
            ev[idx] += xv * xv;
          }
    }
    if (kb == ib) {    // Bt tile currently holds centers[..][..]^T
#pragma unroll
      for (int fr = 0; fr < 2; ++fr)
#pragma unroll
        for (int fc = 0; fc < 2; ++fc)
#pragma unroll
          for (int r = 0; r < 4; ++r) {
            const int idx = ((fr << 1) + fc) * 4 + r;
            const int pr = wr + (fr << 4) + (q4 << 2) + r;
            const int pc = wc + (fc << 4) + l16;
            float cv = bf2f(Blds[pc * PITCH + pr]);
            ev[idx] += cv * cv;
          }
    }

    // ---- MFMA: 2 k-steps of 32 ----
#pragma unroll
    for (int ks = 0; ks < 2; ++ks) {
      const int ko = (ks << 5) + (q4 << 3);
      short8 a0 = *reinterpret_cast<const short8*>(&Alds[(wr +      l16) * PITCH + ko]);
      short8 a1 = *reinterpret_cast<const short8*>(&Alds[(wr + 16 + l16) * PITCH + ko]);
      short8 b0 = *reinterpret_cast<const short8*>(&Blds[(wc +      l16) * PITCH + ko]);
      short8 b1 = *reinterpret_cast<const short8*>(&Blds[(wc + 16 + l16) * PITCH + ko]);
      acc[0][0] = __builtin_amdgcn_mfma_f32_16x16x32_bf16(a0, b0, acc[0][0], 0, 0, 0);
      acc[0][1] = __builtin_amdgcn_mfma_f32_16x16x32_bf16(a0, b1, acc[0][1], 0, 0, 0);
      acc[1][0] = __builtin_amdgcn_mfma_f32_16x16x32_bf16(a1, b0, acc[1][0], 0, 0, 0);
      acc[1][1] = __builtin_amdgcn_mfma_f32_16x16x32_bf16(a1, b1, acc[1][1], 0, 0, 0);
    }

    // ---- channel boundary: online softmax update, reset accumulators ----
    if (kb == 5) {
#pragma unroll
      for (int fr = 0; fr < 2; ++fr)
#pragma unroll
        for (int fc = 0; fc < 2; ++fc)
#pragma unroll
          for (int r = 0; r < 4; ++r) {
            const int idx = ((fr << 1) + fc) * 4 + r;
            float res = ev[idx] - 2.0f * acc[fr][fc][r];
            float mi = m[idx];
            if (res <= mi) {
              s[idx] += __expf(res - mi);
            } else {
              s[idx] = s[idx] * __expf(mi - res) + 1.0f;
              m[idx] = res;
            }
            acc[fr][fc][r] = 0.0f;
            ev[idx] = 0.0f;
          }
    }

    kb = kn; c = cn;
#pragma unroll
    for (int p = 0; p < 4; ++p) pa[p] = na[p];
#pragma unroll
    for (int p = 0; p < 16; ++p) pb[p] = nb[p];
  }

  // ---- max(softmax) = 1/s ; weight by label; clip; reduce ----
  float local = 0.0f;
  const int* lb = Lab + (size_t)n * plane;
#pragma unroll
  for (int fr = 0; fr < 2; ++fr)
#pragma unroll
    for (int fc = 0; fc < 2; ++fc)
#pragma unroll
      for (int r = 0; r < 4; ++r) {
        const int idx = ((fr << 1) + fc) * 4 + r;
        const int pr = i0 + wr + (fr << 4) + (q4 << 2) + r;
        const int pc = j0 + wc + (fc << 4) + l16;
        float val = 1.0f / s[idx];
        float d = val * (float)lb[pr * Ww + pc];
        d = fminf(fmaxf(d, 1e-12f), 1e12f);
        local += d;
      }
#pragma unroll
  for (int off = 32; off > 0; off >>= 1) local += __shfl_down(local, off, 64);
  if (l == 0) red[w] = local;
  __syncthreads();
  if (t == 0) {
    float bs = (red[0] + red[1] + red[2] + red[3]) * (1.0f / 4718592.0f);
    atomicAdd(Out, bs);
  }
}

extern "C" void kernel_launch(void* const* d_in, const int* in_sizes, int n_in,
                              void* d_out, int out_size, void* d_ws, size_t ws_size,
                              hipStream_t stream) {
  const float* X   = (const float*)d_in[0];
  const float* Cen = (const float*)d_in[1];
  const int*   Lab = (const int*)d_in[2];
  float* Out = (float*)d_out;
  hipMemsetAsync(Out, 0, (size_t)out_size * sizeof(float), stream);
  hipLaunchKernelGGL(center_loss, dim3(Nn * 36), dim3(256), 0, stream,
                     X, Cen, Lab, Out);
}

// Round 6
// 488.582 us; speedup vs baseline: 1.3426x; 1.0071x over previous
//
#include <hip/hip_runtime.h>
#include <stdint.h>

typedef __attribute__((ext_vector_type(8))) short short8;
typedef __attribute__((ext_vector_type(4))) float floatx4;
typedef __attribute__((ext_vector_type(2))) uint32_t u32x2;
typedef __attribute__((ext_vector_type(4))) uint32_t u32x4;

#define Hh 384
#define Ww 384
#define Cc 11
#define Nn 32
#define PITCH 72  // 64 + 8 pad bf16 elems; 144 B rows: 16B-aligned

__device__ __forceinline__ float bf2f(unsigned short b) {
  union { uint32_t u; float f; } z; z.u = ((uint32_t)b) << 16;
  return z.f;
}
// (bf16_trunc(hi) << 16) | bf16_trunc(lo) in ONE v_perm_b32 (exact same
// truncation semantics as the verified shift-based f2bf).
__device__ __forceinline__ uint32_t pkbf(float hi, float lo) {
  union { float f; uint32_t u; } a, b; a.f = hi; b.f = lo;
  return __builtin_amdgcn_perm(a.u, b.u, 0x07060302u);
}

// lgkm-only barrier: LDS ordered; global prefetch loads stay in flight.
#define BAR() do {                                          \
    asm volatile("s_waitcnt lgkmcnt(0)" ::: "memory");      \
    __builtin_amdgcn_s_barrier();                           \
    asm volatile("" ::: "memory");                          \
  } while (0)

__global__ __launch_bounds__(256, 3)
void center_loss(const float* __restrict__ X, const float* __restrict__ Cen,
                 const int* __restrict__ Lab, float* __restrict__ Out) {
  __shared__ __align__(16) unsigned short Alds[64 * PITCH];  // A[i][k]  (x rows)
  __shared__ __align__(16) unsigned short Blds[64 * PITCH];  // Bt[j][k] (centers cols)
  __shared__ float red[4];

  // XCD swizzle: all 36 blocks of one n share an XCD.
  const int bx   = blockIdx.x;
  const int xcd  = bx & 7;
  const int slot = bx >> 3;
  const int grp  = slot / 36;
  const int t36  = slot - grp * 36;
  const int n    = xcd + (grp << 3);
  const int ib = t36 / 6;
  const int jb = t36 - ib * 6;
  const int i0 = ib << 6, j0 = jb << 6;

  const int t   = threadIdx.x;
  const int l   = t & 63;
  const int w   = t >> 6;
  const int wr  = (w >> 1) << 5;
  const int wc  = (w & 1) << 5;
  const int q4  = l >> 4;
  const int l16 = l & 15;
  const int sa  = t & 15;            // A staging: col segment
  const int sr  = t >> 4;            // A staging: row base

  const size_t plane = (size_t)Hh * Ww;
  const float* xbase = X   + (size_t)n * Cc * plane;
  const float* cbase = Cen + (size_t)n * Cc * plane;
  // loop-invariant per-lane offsets
  const size_t aoffg = (size_t)(i0 + sr) * Ww + (sa << 2);
  const size_t boffg0 = (size_t)((w << 3) +  0) * Ww + j0 + l;
  const size_t boffg1 = (size_t)((w << 3) + 32) * Ww + j0 + l;

  float m[16], s[16];
#pragma unroll
  for (int i = 0; i < 16; ++i) { m[i] = -3.0e38f; s[i] = 0.0f; }

  floatx4 acc[2][2];
#pragma unroll
  for (int a = 0; a < 2; ++a)
#pragma unroll
    for (int b = 0; b < 2; ++b) acc[a][b] = (floatx4){0.f, 0.f, 0.f, 0.f};

  // Two register tile-buffers, alternated by even/odd unroll (no copies).
  float4 pa[4], na[4];
  float  pb[16], nb[16];

#define LOADT(PA, PB, CC, KK) do {                                             \
    const float* ap_ = xbase + (size_t)(CC) * plane + ((KK) << 6) + aoffg;     \
    PA[0] = *reinterpret_cast<const float4*>(ap_);                             \
    PA[1] = *reinterpret_cast<const float4*>(ap_ + (size_t)16 * Ww);           \
    PA[2] = *reinterpret_cast<const float4*>(ap_ + (size_t)32 * Ww);           \
    PA[3] = *reinterpret_cast<const float4*>(ap_ + (size_t)48 * Ww);           \
    const float* b0_ = cbase + (size_t)(CC) * plane + (size_t)((KK) << 6) * Ww;\
    const float* bp0 = b0_ + boffg0;                                           \
    const float* bp1 = b0_ + boffg1;                                           \
    _Pragma("unroll")                                                          \
    for (int u_ = 0; u_ < 8; ++u_) PB[u_]     = bp0[(size_t)u_ * Ww];          \
    _Pragma("unroll")                                                          \
    for (int u_ = 0; u_ < 8; ++u_) PB[8 + u_] = bp1[(size_t)u_ * Ww];          \
  } while (0)

#define STAGE(PA, PB) do {                                                     \
    _Pragma("unroll")                                                          \
    for (int p_ = 0; p_ < 4; ++p_) {                                           \
      u32x2 pk_;                                                               \
      pk_.x = pkbf(PA[p_].y, PA[p_].x);                                        \
      pk_.y = pkbf(PA[p_].w, PA[p_].z);                                        \
      *reinterpret_cast<u32x2*>(&Alds[(sr + 16 * p_) * PITCH + (sa << 2)]) = pk_; \
    }                                                                          \
    _Pragma("unroll")                                                          \
    for (int p_ = 0; p_ < 2; ++p_) {                                           \
      u32x4 pk_;                                                               \
      pk_.x = pkbf(PB[p_ * 8 + 1], PB[p_ * 8 + 0]);                            \
      pk_.y = pkbf(PB[p_ * 8 + 3], PB[p_ * 8 + 2]);                            \
      pk_.z = pkbf(PB[p_ * 8 + 5], PB[p_ * 8 + 4]);                            \
      pk_.w = pkbf(PB[p_ * 8 + 7], PB[p_ * 8 + 6]);                            \
      *reinterpret_cast<u32x4*>(&Blds[l * PITCH + (w << 3) + (p_ << 5)]) = pk_;\
    }                                                                          \
  } while (0)

  // res = x^2 + c^2 - 2*mm carried as acc = mm - 0.5*(x^2 + c^2); res = -2*acc.
#define COMPUTE() do {                                                         \
    if (kb == jb) { /* A tile cols are j0..j0+63 */                            \
      _Pragma("unroll") for (int fr_ = 0; fr_ < 2; ++fr_)                      \
      _Pragma("unroll") for (int fc_ = 0; fc_ < 2; ++fc_)                      \
      _Pragma("unroll") for (int r_ = 0; r_ < 4; ++r_) {                       \
        const int pr_ = wr + (fr_ << 4) + (q4 << 2) + r_;                      \
        const int pc_ = wc + (fc_ << 4) + l16;                                 \
        float xv_ = bf2f(Alds[pr_ * PITCH + pc_]);                             \
        acc[fr_][fc_][r_] -= 0.5f * xv_ * xv_;                                 \
      }                                                                        \
    }                                                                          \
    if (kb == ib) { /* Bt tile k-range is i0..i0+63 */                         \
      _Pragma("unroll") for (int fr_ = 0; fr_ < 2; ++fr_)                      \
      _Pragma("unroll") for (int fc_ = 0; fc_ < 2; ++fc_)                      \
      _Pragma("unroll") for (int r_ = 0; r_ < 4; ++r_) {                       \
        const int pr_ = wr + (fr_ << 4) + (q4 << 2) + r_;                      \
        const int pc_ = wc + (fc_ << 4) + l16;                                 \
        float cv_ = bf2f(Blds[pc_ * PITCH + pr_]);                             \
        acc[fr_][fc_][r_] -= 0.5f * cv_ * cv_;                                 \
      }                                                                        \
    }                                                                          \
    _Pragma("unroll") for (int ks_ = 0; ks_ < 2; ++ks_) {                      \
      const int ko_ = (ks_ << 5) + (q4 << 3);                                  \
      short8 a0_ = *reinterpret_cast<const short8*>(&Alds[(wr +      l16) * PITCH + ko_]); \
      short8 a1_ = *reinterpret_cast<const short8*>(&Alds[(wr + 16 + l16) * PITCH + ko_]); \
      short8 b0_ = *reinterpret_cast<const short8*>(&Blds[(wc +      l16) * PITCH + ko_]); \
      short8 b1_ = *reinterpret_cast<const short8*>(&Blds[(wc + 16 + l16) * PITCH + ko_]); \
      acc[0][0] = __builtin_amdgcn_mfma_f32_16x16x32_bf16(a0_, b0_, acc[0][0], 0, 0, 0); \
      acc[0][1] = __builtin_amdgcn_mfma_f32_16x16x32_bf16(a0_, b1_, acc[0][1], 0, 0, 0); \
      acc[1][0] = __builtin_amdgcn_mfma_f32_16x16x32_bf16(a1_, b0_, acc[1][0], 0, 0, 0); \
      acc[1][1] = __builtin_amdgcn_mfma_f32_16x16x32_bf16(a1_, b1_, acc[1][1], 0, 0, 0); \
    }                                                                          \
    if (kb == 5) { /* channel boundary: branchless online softmax */           \
      _Pragma("unroll") for (int fr_ = 0; fr_ < 2; ++fr_)                      \
      _Pragma("unroll") for (int fc_ = 0; fc_ < 2; ++fc_)                      \
      _Pragma("unroll") for (int r_ = 0; r_ < 4; ++r_) {                       \
        const int idx_ = ((fr_ << 1) + fc_) * 4 + r_;                          \
        float res_ = -2.0f * acc[fr_][fc_][r_];                                \
        float M_ = fmaxf(m[idx_], res_);                                       \
        s[idx_] = s[idx_] * __expf(m[idx_] - M_) + __expf(res_ - M_);          \
        m[idx_] = M_;                                                          \
        acc[fr_][fc_][r_] = 0.0f;                                              \
      }                                                                        \
    }                                                                          \
    ++kb; if (kb == 6) { kb = 0; ++c; }                                        \
  } while (0)

  // prologue: tile 0 into pa/pb
  LOADT(pa, pb, 0, 0);
  int kb = 0, c = 0;     // compute-tile index
  int kbL = 1, cL = 0;   // next tile to load

  // 66 tiles = 33 even/odd pairs; loads issued one FULL iteration before use.
  for (int mi = 0; mi < 33; ++mi) {
    // even it = 2mi: load tile 2mi+1 -> na, stage pa (tile 2mi), compute
    BAR();
    LOADT(na, nb, cL, kbL);
    ++kbL; if (kbL == 6) { kbL = 0; ++cL; }
    STAGE(pa, pb);
    BAR();
    COMPUTE();
    // odd it = 2mi+1: load tile 2mi+2 -> pa (if any), stage na, compute
    BAR();
    if (mi < 32) {
      LOADT(pa, pb, cL, kbL);
      ++kbL; if (kbL == 6) { kbL = 0; ++cL; }
    }
    STAGE(na, nb);
    BAR();
    COMPUTE();
  }

  // ---- max(softmax) = 1/s ; weight by label; clip; reduce ----
  float local = 0.0f;
  const int* lb = Lab + (size_t)n * plane;
#pragma unroll
  for (int fr = 0; fr < 2; ++fr)
#pragma unroll
    for (int fc = 0; fc < 2; ++fc)
#pragma unroll
      for (int r = 0; r < 4; ++r) {
        const int idx = ((fr << 1) + fc) * 4 + r;
        const int pr = i0 + wr + (fr << 4) + (q4 << 2) + r;
        const int pc = j0 + wc + (fc << 4) + l16;
        float val = 1.0f / s[idx];
        float d = val * (float)lb[pr * Ww + pc];
        d = fminf(fmaxf(d, 1e-12f), 1e12f);
        local += d;
      }
#pragma unroll
  for (int off = 32; off > 0; off >>= 1) local += __shfl_down(local, off, 64);
  if (l == 0) red[w] = local;
  __syncthreads();
  if (t == 0) {
    float bs = (red[0] + red[1] + red[2] + red[3]) * (1.0f / 4718592.0f);
    atomicAdd(Out, bs);
  }
}

extern "C" void kernel_launch(void* const* d_in, const int* in_sizes, int n_in,
                              void* d_out, int out_size, void* d_ws, size_t ws_size,
                              hipStream_t stream) {
  const float* X   = (const float*)d_in[0];
  const float* Cen = (const float*)d_in[1];
  const int*   Lab = (const int*)d_in[2];
  float* Out = (float*)d_out;
  hipMemsetAsync(Out, 0, (size_t)out_size * sizeof(float), stream);
  hipLaunchKernelGGL(center_loss, dim3(Nn * 36), dim3(256), 0, stream,
                     X, Cen, Lab, Out);
}